// Round 5
// baseline (270.300 us; speedup 1.0000x reference)
//
#include <hip/hip_runtime.h>
#include <math.h>

// R5: occupancy + epilogue-VALU attack on R4's latency bound.
// R4 counters: VALUBusy 29%, HBM 10%, Occupancy 13.5%, conflicts 1.1M ->
// latency-bound at 3 blocks/CU; LDS (45.5KB) is the occupancy binder
// (VGPR 68 would allow 7 waves/SIMD). Epilogue ~40% of VALU, mostly libm
// atan2f (~35 ops + IEEE divide) against a 1.05-rad phase threshold.
// Changes:
//  1) Two 8-frame passes through an 8-frame Z (16.5KB): LDS 45.5->28.8KB
//     -> 5 blocks/CU (20 waves). Phase-1 register FFT still done once for
//     all 16 frames (a[] stays live through pass A for tl>=8 threads).
//     Phase-2/unpack are column-private per thread -> split adds only
//     3 barriers. Pass A/B hit the same out 128B lines -> L2 merges.
//  2) fast_atan2: deg-11 odd minimax (err ~2.4e-6 rad << 1.05) + v_rcp,
//     ~12 ops vs ~35. Branch-cut patch unchanged (sign of i+eps comes from
//     the bit-exact v5 sequential-fmaf recompute; poly preserves the side).
// Everything else identical to R4 (verified numerics).

#define BATCH 16
#define NSAMP 160000
#define NF 257
#define NT 1603
#define KLEN 400
#define INC 100
#define PADL 300
#define EPSF 1.1920928955078125e-7f
#define TAU 1e-2f

#define FPB 16                            // frames per block
#define ZSTR 258                          // complex stride per frame row
#define XSPAN ((FPB - 1) * INC + KLEN)    // 1900
#define NTB ((NT + FPB - 1) / FPB)        // 101

__device__ __forceinline__ float2 cmul(float2 a, float2 b) {
  return make_float2(a.x * b.x - a.y * b.y, a.x * b.y + a.y * b.x);
}

// 16-point DIF FFT in registers; output a[r] = F[brev4(r)].
__device__ __forceinline__ void fft16_dif(float2* a) {
  const float C1 = 0.92387953251128674f;   // cos(pi/8)
  const float S1 = 0.38268343236508978f;   // sin(pi/8)
  const float R2 = 0.70710678118654752f;   // sqrt(2)/2
  {                                        // span 8, tw = w16^j
    const float2 W[8] = {{1.f, 0.f},  {C1, -S1},  {R2, -R2},  {S1, -C1},
                         {0.f, -1.f}, {-S1, -C1}, {-R2, -R2}, {-C1, -S1}};
    #pragma unroll
    for (int j = 0; j < 8; ++j) {
      float2 u = a[j], v = a[j + 8];
      a[j] = make_float2(u.x + v.x, u.y + v.y);
      float2 d = make_float2(u.x - v.x, u.y - v.y);
      a[j + 8] = cmul(d, W[j]);
    }
  }
  {                                        // span 4, tw = w8^j
    const float2 W[4] = {{1.f, 0.f}, {R2, -R2}, {0.f, -1.f}, {-R2, -R2}};
    #pragma unroll
    for (int h = 0; h < 16; h += 8)
      #pragma unroll
      for (int j = 0; j < 4; ++j) {
        float2 u = a[h + j], v = a[h + j + 4];
        a[h + j] = make_float2(u.x + v.x, u.y + v.y);
        float2 d = make_float2(u.x - v.x, u.y - v.y);
        a[h + j + 4] = cmul(d, W[j]);
      }
  }
  #pragma unroll
  for (int q = 0; q < 16; q += 4) {        // span 2, tw = {1, -i}
    float2 u0 = a[q], v0 = a[q + 2];
    a[q] = make_float2(u0.x + v0.x, u0.y + v0.y);
    a[q + 2] = make_float2(u0.x - v0.x, u0.y - v0.y);
    float2 u1 = a[q + 1], v1 = a[q + 3];
    a[q + 1] = make_float2(u1.x + v1.x, u1.y + v1.y);
    float2 d = make_float2(u1.x - v1.x, u1.y - v1.y);
    a[q + 3] = make_float2(d.y, -d.x);     // *(-i)
  }
  #pragma unroll
  for (int q = 0; q < 16; q += 2) {        // span 1
    float2 u = a[q], v = a[q + 1];
    a[q] = make_float2(u.x + v.x, u.y + v.y);
    a[q + 1] = make_float2(u.x - v.x, u.y - v.y);
  }
}

// atan2 via deg-11 odd minimax on [0,1] (max err ~2.4e-6 rad; thr = 1.05).
__device__ __forceinline__ float fast_atan2(float y, float x) {
  float ax = fabsf(x), ay = fabsf(y);
  float mx = fmaxf(ax, ay), mn = fminf(ax, ay);
  float t = mn * __builtin_amdgcn_rcpf(fmaxf(mx, 1e-37f));
  float s = t * t;
  float p = fmaf(s, -0.01172120f, 0.05265332f);
  p = fmaf(s, p, -0.11643287f);
  p = fmaf(s, p, 0.19354346f);
  p = fmaf(s, p, -0.33262347f);
  p = fmaf(s, p, 0.99997726f);
  float r = t * p;
  if (ay > ax) r = 1.57079632679489662f - r;
  if (x < 0.f) r = 3.14159265358979324f - r;
  return (y < 0.f) ? -r : r;
}

// mag/phase emit with the R3 branch-cut exactness patch (sequential-k fmaf).
__device__ __forceinline__ void emit_fp(float rr, float ii, int ff,
                                        const float* __restrict__ w,
                                        const float* xf,
                                        float* __restrict__ out,
                                        long o, long plane) {
  float ie = ii + EPSF, re = rr + EPSF;
  if (fabsf(ie) < TAU && re < TAU) {       // cold path, ~few pts/block
    const float* wr = w + (long)ff * KLEN;
    const float* wi = w + (long)(257 + ff) * KLEN;
    float r2 = 0.f, i2 = 0.f;
    for (int k = 0; k < KLEN; ++k) {       // sequential, k ascending (v5 order)
      float xv = xf[k];
      r2 = fmaf(wr[k], xv, r2);
      i2 = fmaf(wi[k], xv, i2);
    }
    rr = r2; ii = i2;
  }
  out[o] = sqrtf(fmaxf(rr * rr + ii * ii, EPSF));
  out[o + plane] = fast_atan2(ii + EPSF, rr + EPSF);
}

__global__ __launch_bounds__(256, 5)
void stft_fft5(const float* __restrict__ x, const float* __restrict__ w,
               float* __restrict__ out) {
  __shared__ float2 Z[8 * ZSTR];            // 16512 B: 8-frame transpose/spec
  __shared__ float2 tw[132];                // e^{-2pi i p/512}, p<=128
  __shared__ float2 tw256[256];             // e^{-2pi i j/256}
  __shared__ __align__(16) float xs[XSPAN]; // zero-padded input window
  __shared__ __align__(16) float win[KLEN]; // = W row 0 exactly

  const int tid = threadIdx.x;
  const int t0 = blockIdx.x * FPB;
  const int b = blockIdx.y;
  const int tl = tid & 15;                  // frame
  const int th = tid >> 4;                  // worker: n2 (phase1) = k1 (phase2)

  // ---- stage xs (vectorized, zero-padded), window, twiddle tables ----
  const long xb = (long)b * NSAMP;
  const int base = t0 * INC - PADL;
  for (int r = 0; r < 2; ++r) {
    int i4 = r * 256 + tid;
    if (4 * i4 < XSPAN) {
      int g = base + 4 * i4;
      float4 v;
      if (g >= 0 && g + 3 < NSAMP) {
        v = *(const float4*)(x + xb + g);
      } else {
        v.x = (g + 0 >= 0 && g + 0 < NSAMP) ? x[xb + g + 0] : 0.f;
        v.y = (g + 1 >= 0 && g + 1 < NSAMP) ? x[xb + g + 1] : 0.f;
        v.z = (g + 2 >= 0 && g + 2 < NSAMP) ? x[xb + g + 2] : 0.f;
        v.w = (g + 3 >= 0 && g + 3 < NSAMP) ? x[xb + g + 3] : 0.f;
      }
      *(float4*)&xs[4 * i4] = v;
    }
  }
  if (tid < KLEN / 4) {                     // W[0][k] = fp32(hamming) exactly
    *(float4*)&win[4 * tid] = *(const float4*)(w + 4 * tid);
  }
  {
    double a = (double)tid * (6.283185307179586476925286766559 / 256.0);
    tw256[tid] = make_float2((float)cos(a), (float)(-sin(a)));
  }
  if (tid < 132) {
    double a = (double)tid * (6.283185307179586476925286766559 / 512.0);
    tw[tid] = make_float2((float)cos(a), (float)(-sin(a)));
  }
  __syncthreads();

  // ---- phase 1: windowed load z[16*n1+th] -> register FFT over n1 ----
  float2 a[16];
  const float* xf = &xs[tl * INC];
  #pragma unroll
  for (int n1 = 0; n1 < 12; ++n1) {         // n = 32*n1+2*th <= 382 < 400
    int n = 32 * n1 + 2 * th;
    float2 xv = *(const float2*)&xf[n];
    float2 wv = *(const float2*)&win[n];
    a[n1] = make_float2(xv.x * wv.x, xv.y * wv.y);
  }
  {
    int n = 384 + 2 * th;                   // n1 = 12: valid iff th <= 7
    if (n < KLEN) {
      float2 xv = *(const float2*)&xf[n];
      float2 wv = *(const float2*)&win[n];
      a[12] = make_float2(xv.x * wv.x, xv.y * wv.y);
    } else {
      a[12] = make_float2(0.f, 0.f);
    }
  }
  a[13] = a[14] = a[15] = make_float2(0.f, 0.f);   // y[n]=0, n>=416

  fft16_dif(a);                             // a[r] = F1[th][brev4(r)]

  static const int BR[16] = {0, 8, 4, 12, 2, 10, 6, 14,
                             1, 9, 5, 13, 3, 11, 7, 15};
  const long plane = (long)BATCH * NF * NT;
  const long pb = (long)b * NF * NT;

  // ---- two 8-frame passes through the 8-frame Z ----
  #pragma unroll 1
  for (int hp = 0; hp < 2; ++hp) {
    const bool mine = ((tl >> 3) == hp);
    float2* Zf = Z + (tl & 7) * ZSTR;
    if (mine) {
      #pragma unroll
      for (int r = 0; r < 16; ++r) {        // x w256^{th*k1}, transpose-store
        const int k1 = BR[r];
        float2 v = (k1 == 0) ? a[r] : cmul(a[r], tw256[th * k1]);
        Zf[th * 16 + k1] = v;
      }
    }
    __syncthreads();
    if (mine) {                             // column-private: in-place safe
      float2 g[16];
      #pragma unroll
      for (int n2 = 0; n2 < 16; ++n2) g[n2] = Zf[n2 * 16 + th];
      fft16_dif(g);                         // g[r] = Z[16*brev4(r) + th]
      #pragma unroll
      for (int r = 0; r < 16; ++r) {
        const int k2 = BR[r];
        Zf[16 * k2 + th] = g[r];            // natural-order spectrum
      }
    }
    __syncthreads();

    // ---- fused rFFT-unpack + mag/phase + coalesced store (8 frames) ----
    for (int r = 0; r < 5; ++r) {
      int tau = r * 256 + tid;
      if (tau < 8 * 129) {
        int t8 = tau & 7;
        int p = tau >> 3;                   // 0..128
        float2* Zt = Z + t8 * ZSTR;
        float2 z0 = Zt[p];
        float2 z1 = Zt[(256 - p) & 255];
        float2 ze = make_float2(0.5f * (z0.x + z1.x), 0.5f * (z0.y - z1.y));
        float2 zo = make_float2(0.5f * (z0.y + z1.y), 0.5f * (z1.x - z0.x));
        float2 T = tw[p];
        float2 tz = cmul(zo, T);
        float2 ya = make_float2(ze.x + tz.x, ze.y + tz.y);        // Y[p]
        float2 yb = make_float2(ze.x - tz.x, tz.y - ze.y);        // Y[256-p]
        int t = hp * 8 + t8;
        int tt = t0 + t;
        if (tt < NT) {
          const float* xfr = &xs[t * INC];
          emit_fp(ya.x, ya.y, p, w, xfr, out, pb + (long)p * NT + tt, plane);
          if (p == 0) {
            emit_fp(yb.x, 0.f, 256, w, xfr, out,
                    pb + (long)256 * NT + tt, plane);
          } else {
            emit_fp(yb.x, yb.y, 256 - p, w, xfr, out,
                    pb + (long)(256 - p) * NT + tt, plane);
          }
        }
      }
    }
    __syncthreads();                        // Z reused by next pass
  }
}

extern "C" void kernel_launch(void* const* d_in, const int* in_sizes, int n_in,
                              void* d_out, int out_size, void* d_ws, size_t ws_size,
                              hipStream_t stream) {
  const float* x = (const float*)d_in[0];   // (16, 160000) fp32
  const float* w = (const float*)d_in[1];   // (514, 1, 400) fp32
  float* out = (float*)d_out;

  dim3 grid(NTB, BATCH);                    // 101 x 16 = 1616 blocks
  stft_fft5<<<grid, dim3(256), 0, stream>>>(x, w, out);
}

// Round 6
// 236.278 us; speedup vs baseline: 1.1440x; 1.1440x over previous
//
#include <hip/hip_runtime.h>
#include <math.h>

// R6: wave-uniform two-pass, contained register lifetimes.
// R5 post-mortem: holding a[16] (32 VGPRs) live across the call-heavy pass-A
// epilogue under launch_bounds(256,5) made the allocator spill to scratch
// (VGPR 68->48, FETCH 9.6->182MB, WRITE 74->322MB, VALUBusy 15%) -> 2.3x
// regression. Fix: phase-1 runs INSIDE each pass, executed only by that
// pass's waves; frame = tid>>4 (wave-uniform pass split, no lane divergence);
// a[]/g[] live only within a pass -> no long ranges -> no spill.
// FPB=32 / 512 threads: two 16-frame passes through ONE 16-frame Z.
//  - LDS 50.5KB -> 3 blocks/CU x 8 waves = 24 waves/CU (2x R4).
//  - stores stay 64B per f-row per pass (R4's proven write granularity).
//  - frame-major map makes the transpose store same-bank (worker*16 stride);
//    fixed with XOR column swizzle col' = col ^ row on phase-1 store +
//    phase-2 read. Phase-2 store & epilogue reads linear, conflict-free.
// fast_atan2 (deg-11 minimax, err ~2.4e-6 << 1.05 thr) and the bit-exact
// sequential-fmaf branch-cut patch kept (both validated by R5's pass).

#define BATCH 16
#define NSAMP 160000
#define NF 257
#define NT 1603
#define KLEN 400
#define INC 100
#define PADL 300
#define EPSF 1.1920928955078125e-7f
#define TAU 1e-2f

#define FPB 32                            // frames per block (two passes of 16)
#define ZSTR 258                          // complex stride per frame row
#define XSPAN ((FPB - 1) * INC + KLEN)    // 3500
#define NTB ((NT + FPB - 1) / FPB)        // 51

__device__ __forceinline__ float2 cmul(float2 a, float2 b) {
  return make_float2(a.x * b.x - a.y * b.y, a.x * b.y + a.y * b.x);
}

// 16-point DIF FFT in registers; output a[r] = F[brev4(r)].
__device__ __forceinline__ void fft16_dif(float2* a) {
  const float C1 = 0.92387953251128674f;   // cos(pi/8)
  const float S1 = 0.38268343236508978f;   // sin(pi/8)
  const float R2 = 0.70710678118654752f;   // sqrt(2)/2
  {                                        // span 8, tw = w16^j
    const float2 W[8] = {{1.f, 0.f},  {C1, -S1},  {R2, -R2},  {S1, -C1},
                         {0.f, -1.f}, {-S1, -C1}, {-R2, -R2}, {-C1, -S1}};
    #pragma unroll
    for (int j = 0; j < 8; ++j) {
      float2 u = a[j], v = a[j + 8];
      a[j] = make_float2(u.x + v.x, u.y + v.y);
      float2 d = make_float2(u.x - v.x, u.y - v.y);
      a[j + 8] = cmul(d, W[j]);
    }
  }
  {                                        // span 4, tw = w8^j
    const float2 W[4] = {{1.f, 0.f}, {R2, -R2}, {0.f, -1.f}, {-R2, -R2}};
    #pragma unroll
    for (int h = 0; h < 16; h += 8)
      #pragma unroll
      for (int j = 0; j < 4; ++j) {
        float2 u = a[h + j], v = a[h + j + 4];
        a[h + j] = make_float2(u.x + v.x, u.y + v.y);
        float2 d = make_float2(u.x - v.x, u.y - v.y);
        a[h + j + 4] = cmul(d, W[j]);
      }
  }
  #pragma unroll
  for (int q = 0; q < 16; q += 4) {        // span 2, tw = {1, -i}
    float2 u0 = a[q], v0 = a[q + 2];
    a[q] = make_float2(u0.x + v0.x, u0.y + v0.y);
    a[q + 2] = make_float2(u0.x - v0.x, u0.y - v0.y);
    float2 u1 = a[q + 1], v1 = a[q + 3];
    a[q + 1] = make_float2(u1.x + v1.x, u1.y + v1.y);
    float2 d = make_float2(u1.x - v1.x, u1.y - v1.y);
    a[q + 3] = make_float2(d.y, -d.x);     // *(-i)
  }
  #pragma unroll
  for (int q = 0; q < 16; q += 2) {        // span 1
    float2 u = a[q], v = a[q + 1];
    a[q] = make_float2(u.x + v.x, u.y + v.y);
    a[q + 1] = make_float2(u.x - v.x, u.y - v.y);
  }
}

// atan2 via deg-11 odd minimax on [0,1] (max err ~2.4e-6 rad; thr = 1.05).
__device__ __forceinline__ float fast_atan2(float y, float x) {
  float ax = fabsf(x), ay = fabsf(y);
  float mx = fmaxf(ax, ay), mn = fminf(ax, ay);
  float t = mn * __builtin_amdgcn_rcpf(fmaxf(mx, 1e-37f));
  float s = t * t;
  float p = fmaf(s, -0.01172120f, 0.05265332f);
  p = fmaf(s, p, -0.11643287f);
  p = fmaf(s, p, 0.19354346f);
  p = fmaf(s, p, -0.33262347f);
  p = fmaf(s, p, 0.99997726f);
  float r = t * p;
  if (ay > ax) r = 1.57079632679489662f - r;
  if (x < 0.f) r = 3.14159265358979324f - r;
  return (y < 0.f) ? -r : r;
}

// mag/phase emit with the R3 branch-cut exactness patch (sequential-k fmaf).
__device__ __forceinline__ void emit_fp(float rr, float ii, int ff,
                                        const float* __restrict__ w,
                                        const float* xf,
                                        float* __restrict__ out,
                                        long o, long plane) {
  float ie = ii + EPSF, re = rr + EPSF;
  if (fabsf(ie) < TAU && re < TAU) {       // cold path, ~few pts/block
    const float* wr = w + (long)ff * KLEN;
    const float* wi = w + (long)(257 + ff) * KLEN;
    float r2 = 0.f, i2 = 0.f;
    for (int k = 0; k < KLEN; ++k) {       // sequential, k ascending (v5 order)
      float xv = xf[k];
      r2 = fmaf(wr[k], xv, r2);
      i2 = fmaf(wi[k], xv, i2);
    }
    rr = r2; ii = i2;
  }
  out[o] = sqrtf(fmaxf(rr * rr + ii * ii, EPSF));
  out[o + plane] = fast_atan2(ii + EPSF, rr + EPSF);
}

__global__ __launch_bounds__(512, 6)
void stft_fft6(const float* __restrict__ x, const float* __restrict__ w,
               float* __restrict__ out) {
  __shared__ float2 Z[16 * ZSTR];           // 33024 B: 16-frame transpose/spec
  __shared__ float2 tw[132];                // e^{-2pi i p/512}, p<=128
  __shared__ float2 tw256[256];             // e^{-2pi i j/256}
  __shared__ __align__(16) float xs[XSPAN]; // zero-padded input window
  __shared__ __align__(16) float win[KLEN]; // = W row 0 exactly

  const int tid = threadIdx.x;
  const int t0 = blockIdx.x * FPB;
  const int b = blockIdx.y;
  const int fr = tid >> 4;                  // frame 0..31 (wave-uniform sets)
  const int th = tid & 15;                  // worker: n2 (ph1) = k1 (ph2)

  // ---- stage xs (vectorized, zero-padded), window, twiddle tables ----
  const long xb = (long)b * NSAMP;
  const int base = t0 * INC - PADL;
  for (int r = 0; r < 2; ++r) {
    int i4 = r * 512 + tid;
    if (4 * i4 < XSPAN) {
      int g = base + 4 * i4;
      float4 v;
      if (g >= 0 && g + 3 < NSAMP) {
        v = *(const float4*)(x + xb + g);
      } else {
        v.x = (g + 0 >= 0 && g + 0 < NSAMP) ? x[xb + g + 0] : 0.f;
        v.y = (g + 1 >= 0 && g + 1 < NSAMP) ? x[xb + g + 1] : 0.f;
        v.z = (g + 2 >= 0 && g + 2 < NSAMP) ? x[xb + g + 2] : 0.f;
        v.w = (g + 3 >= 0 && g + 3 < NSAMP) ? x[xb + g + 3] : 0.f;
      }
      *(float4*)&xs[4 * i4] = v;
    }
  }
  if (tid < KLEN / 4) {                     // W[0][k] = fp32(hamming) exactly
    *(float4*)&win[4 * tid] = *(const float4*)(w + 4 * tid);
  }
  if (tid < 256) {
    double a = (double)tid * (6.283185307179586476925286766559 / 256.0);
    tw256[tid] = make_float2((float)cos(a), (float)(-sin(a)));
  }
  if (tid < 132) {
    double a = (double)tid * (6.283185307179586476925286766559 / 512.0);
    tw[tid] = make_float2((float)cos(a), (float)(-sin(a)));
  }
  __syncthreads();

  static const int BR[16] = {0, 8, 4, 12, 2, 10, 6, 14,
                             1, 9, 5, 13, 3, 11, 7, 15};
  const long plane = (long)BATCH * NF * NT;
  const long pb = (long)b * NF * NT;

  // ---- two 16-frame passes; pass hp owned by waves with fr>>4 == hp ----
  #pragma unroll 1
  for (int hp = 0; hp < 2; ++hp) {
    const bool mine = ((fr >> 4) == hp);    // whole waves -> no divergence
    float2* Zf = Z + (fr & 15) * ZSTR;
    if (mine) {
      // phase 1: windowed load z[16*n1+th] -> register FFT over n1
      float2 a[16];
      const float* xf = &xs[fr * INC];
      #pragma unroll
      for (int n1 = 0; n1 < 12; ++n1) {     // n = 32*n1+2*th <= 382 < 400
        int n = 32 * n1 + 2 * th;
        float2 xv = *(const float2*)&xf[n];
        float2 wv = *(const float2*)&win[n];
        a[n1] = make_float2(xv.x * wv.x, xv.y * wv.y);
      }
      {
        int n = 384 + 2 * th;               // n1 = 12: valid iff th <= 7
        if (n < KLEN) {
          float2 xv = *(const float2*)&xf[n];
          float2 wv = *(const float2*)&win[n];
          a[12] = make_float2(xv.x * wv.x, xv.y * wv.y);
        } else {
          a[12] = make_float2(0.f, 0.f);
        }
      }
      a[13] = a[14] = a[15] = make_float2(0.f, 0.f);  // y[n]=0, n>=416

      fft16_dif(a);                         // a[r] = F1[th][brev4(r)]

      #pragma unroll
      for (int r = 0; r < 16; ++r) {        // x w256^{th*k1}, swizzled store
        const int k1 = BR[r];
        float2 v = (k1 == 0) ? a[r] : cmul(a[r], tw256[th * k1]);
        Zf[th * 16 + (k1 ^ th)] = v;        // col' = col ^ row: conflict-free
      }
    }
    __syncthreads();
    if (mine) {
      // phase 2: swizzled column read -> register FFT over n2
      float2 g[16];
      #pragma unroll
      for (int n2 = 0; n2 < 16; ++n2) g[n2] = Zf[n2 * 16 + (th ^ n2)];
      fft16_dif(g);                         // g[r] = Z[16*brev4(r) + th]
      #pragma unroll
      for (int r = 0; r < 16; ++r) {
        const int k2 = BR[r];
        Zf[16 * k2 + th] = g[r];            // natural order, conflict-free
      }
    }
    __syncthreads();

    // ---- fused rFFT-unpack + mag/phase + coalesced store (16 frames) ----
    for (int r = 0; r < 5; ++r) {
      int tau = r * 512 + tid;
      if (tau < 16 * 129) {
        int t16 = tau & 15;
        int p = tau >> 4;                   // 0..128
        float2* Zt = Z + t16 * ZSTR;
        float2 z0 = Zt[p];
        float2 z1 = Zt[(256 - p) & 255];
        float2 ze = make_float2(0.5f * (z0.x + z1.x), 0.5f * (z0.y - z1.y));
        float2 zo = make_float2(0.5f * (z0.y + z1.y), 0.5f * (z1.x - z0.x));
        float2 T = tw[p];
        float2 tz = cmul(zo, T);
        float2 ya = make_float2(ze.x + tz.x, ze.y + tz.y);        // Y[p]
        float2 yb = make_float2(ze.x - tz.x, tz.y - ze.y);        // Y[256-p]
        int t = hp * 16 + t16;
        int tt = t0 + t;
        if (tt < NT) {
          const float* xfr = &xs[t * INC];
          emit_fp(ya.x, ya.y, p, w, xfr, out, pb + (long)p * NT + tt, plane);
          if (p == 0) {
            emit_fp(yb.x, 0.f, 256, w, xfr, out,
                    pb + (long)256 * NT + tt, plane);
          } else {
            emit_fp(yb.x, yb.y, 256 - p, w, xfr, out,
                    pb + (long)(256 - p) * NT + tt, plane);
          }
        }
      }
    }
    __syncthreads();                        // Z reused by next pass
  }
}

extern "C" void kernel_launch(void* const* d_in, const int* in_sizes, int n_in,
                              void* d_out, int out_size, void* d_ws, size_t ws_size,
                              hipStream_t stream) {
  const float* x = (const float*)d_in[0];   // (16, 160000) fp32
  const float* w = (const float*)d_in[1];   // (514, 1, 400) fp32
  float* out = (float*)d_out;

  dim3 grid(NTB, BATCH);                    // 51 x 16 = 816 blocks
  stft_fft6<<<grid, dim3(512), 0, stream>>>(x, w, out);
}

// Round 7
// 232.477 us; speedup vs baseline: 1.1627x; 1.0164x over previous
//
#include <hip/hip_runtime.h>
#include <math.h>

// R7: wave-level shuffle FFT — 4 complex regs/lane, no LDS transpose, no
// FFT barriers, occupancy without VGPR caps.
// R5/R6 lesson: the 16-reg-per-thread register FFT spills under any
// tightened launch_bounds (R6: cap 85 -> VGPR 40 + 300MB scratch traffic).
// Fix: one WAVE computes one frame's 256-pt FFT with n = l + 64j:
//   radix-4 within lane (j) -> x w256^{l*k1} (lane consts) -> 64-pt DIF FFT
//   ACROSS lanes via 6 shfl_xor stages (m=32..1, per-lane const twiddles).
// Lane l ends with Z[4*brev6(l)+c], c=0..3. rFFT unpack in-register:
// partner 256-p = lane l^63 slot 4-c (brev6(l^63)=63-brev6(l)); k1=0 chain
// via one bpermute. mag/phase (+ bit-exact seq-fmaf branch-cut patch,
// R3-validated) computed here, scatter-stored to LDS at col=K2+64c (K2
// bijective over lanes -> conflict-free), then coalesced flush.
// Block: 256 thr = 4 waves x 2 frames = 8 frames; LDS 24.5KB -> 6 blocks/CU
// (24 waves, 2x R4); launch_bounds(256,4) -> cap 128, NO forced pressure.
// Bijective XCD swizzle (n=201: q=25,r=1) for L2 write-merge of 32B rows.

#define BATCH 16
#define NSAMP 160000
#define NF 257
#define NT 1603
#define KLEN 400
#define INC 100
#define EPSF 1.1920928955078125e-7f
#define TAU 1e-2f

#define FPB 8                             // frames per block
#define XSPAN ((FPB - 1) * INC + KLEN)    // 1100
#define NTB ((NT + FPB - 1) / FPB)        // 201
#define MPLD 257

__device__ __forceinline__ float2 cmul(float2 a, float2 b) {
  return make_float2(a.x * b.x - a.y * b.y, a.x * b.y + a.y * b.x);
}
__device__ __forceinline__ float2 sx(float2 v, int m) {
  return make_float2(__shfl_xor(v.x, m), __shfl_xor(v.y, m));
}

// atan2 via deg-11 odd minimax on [0,1] (max err ~2.4e-6 rad; thr = 1.05).
__device__ __forceinline__ float fast_atan2(float y, float x) {
  float ax = fabsf(x), ay = fabsf(y);
  float mx = fmaxf(ax, ay), mn = fminf(ax, ay);
  float t = mn * __builtin_amdgcn_rcpf(fmaxf(mx, 1e-37f));
  float s = t * t;
  float p = fmaf(s, -0.01172120f, 0.05265332f);
  p = fmaf(s, p, -0.11643287f);
  p = fmaf(s, p, 0.19354346f);
  p = fmaf(s, p, -0.33262347f);
  p = fmaf(s, p, 0.99997726f);
  float r = t * p;
  if (ay > ax) r = 1.57079632679489662f - r;
  if (x < 0.f) r = 3.14159265358979324f - r;
  return (y < 0.f) ? -r : r;
}

// mag/phase -> LDS rows, with the R3 bit-exact branch-cut patch.
__device__ __forceinline__ void emitMP(float rr, float ii, int p, int col,
                                       const float* xf,
                                       const float* __restrict__ w,
                                       float* mrow, float* prow) {
  float ie = ii + EPSF, re = rr + EPSF;
  if (fabsf(ie) < TAU && re < TAU && !(rr == 0.f && ii == 0.f)) {
    const float* wr = w + (long)p * KLEN;
    const float* wi = w + (long)(257 + p) * KLEN;
    float r2 = 0.f, i2 = 0.f;
    for (int k = 0; k < KLEN; ++k) {      // sequential k (v5 rounding class)
      float xv = xf[k];
      r2 = fmaf(wr[k], xv, r2);
      i2 = fmaf(wi[k], xv, i2);
    }
    rr = r2; ii = i2;
  }
  mrow[col] = sqrtf(fmaxf(rr * rr + ii * ii, EPSF));
  prow[col] = fast_atan2(ii + EPSF, rr + EPSF);
}

// Y[p] = Ze + T*Zo from z0=Z[p], z1=Z[(256-p)&255]; valid for all p in [0,256).
__device__ __forceinline__ void emitY(float2 z0, float2 z1, float2 T,
                                      int p, int col, const float* xf,
                                      const float* __restrict__ w,
                                      float* mrow, float* prow) {
  float2 ze = make_float2(0.5f * (z0.x + z1.x), 0.5f * (z0.y - z1.y));
  float2 zo = make_float2(0.5f * (z0.y + z1.y), 0.5f * (z1.x - z0.x));
  float2 tz = cmul(zo, T);
  emitMP(ze.x + tz.x, ze.y + tz.y, p, col, xf, w, mrow, prow);
}

#define LSTG(VV, HH, MM, TWW) { float2 o_ = sx(VV, MM);                     \
  float2 su_ = make_float2(VV.x + o_.x, VV.y + o_.y);                       \
  float2 df_ = make_float2(o_.x - VV.x, o_.y - VV.y);                       \
  VV = HH ? cmul(df_, TWW) : su_; }
#define LSTGN(VV, HH, MM) { float2 o_ = sx(VV, MM);                         \
  float2 su_ = make_float2(VV.x + o_.x, VV.y + o_.y);                       \
  float2 df_ = make_float2(o_.x - VV.x, o_.y - VV.y);                       \
  VV = HH ? df_ : su_; }

__global__ __launch_bounds__(256, 4)
void stft_fft7(const float* __restrict__ x, const float* __restrict__ w,
               float* __restrict__ out) {
  __shared__ float magb[FPB * MPLD];        // 8224 B
  __shared__ float phb[FPB * MPLD];         // 8224 B
  __shared__ float2 tw256[256];             // 2048 B: e^{-2pi i j/256}
  __shared__ __align__(16) float xs[XSPAN]; // 4400 B
  __shared__ __align__(16) float win[KLEN]; // 1600 B   (total ~24.5 KB)

  const int tid = threadIdx.x;
  const int l = tid & 63;
  const int wv = tid >> 6;
  const int b = blockIdx.y;

  // bijective XCD swizzle over t-chunks (n=201: q=25, r=1; m204 form)
  const int orig = blockIdx.x;
  const int xcd = orig & 7;
  const int tb = ((xcd == 0) ? 0 : (26 + (xcd - 1) * 25)) + (orig >> 3);
  const int t0 = tb * FPB;

  // ---- stage xs (zero-padded), win, tw256 ----
  const long xb = (long)b * NSAMP;
  const int base = t0 * INC - 300;
  for (int i4 = tid; i4 < XSPAN / 4; i4 += 256) {
    int g = base + 4 * i4;
    float4 v;
    if (g >= 0 && g + 3 < NSAMP) {
      v = *(const float4*)(x + xb + g);
    } else {
      v.x = (g + 0 >= 0 && g + 0 < NSAMP) ? x[xb + g + 0] : 0.f;
      v.y = (g + 1 >= 0 && g + 1 < NSAMP) ? x[xb + g + 1] : 0.f;
      v.z = (g + 2 >= 0 && g + 2 < NSAMP) ? x[xb + g + 2] : 0.f;
      v.w = (g + 3 >= 0 && g + 3 < NSAMP) ? x[xb + g + 3] : 0.f;
    }
    *(float4*)&xs[4 * i4] = v;
  }
  if (tid < KLEN / 4) {                     // W row 0 = fp32(hamming) exactly
    *(float4*)&win[4 * tid] = *(const float4*)(w + 4 * tid);
  }
  {
    double a = (double)tid * (6.283185307179586476925286766559 / 256.0);
    tw256[tid] = make_float2((float)cos(a), (float)(-sin(a)));
  }
  __syncthreads();

  // ---- per-lane constants (frame-independent) ----
  const int K2 = __brev((unsigned)l) >> 26;             // brev6(l)
  const float2 TW0 = tw256[(l & 31) * 4];               // stage m=32
  const float2 TW1 = tw256[(l & 15) * 8];               // m=16
  const float2 TW2 = tw256[(l & 7) * 16];               // m=8
  const float2 TW3 = tw256[(l & 3) * 32];               // m=4
  const float2 TW4 = tw256[(l & 1) * 64];               // m=2
  const float2 T1 = tw256[l];                           // w256^l
  const float2 T2 = tw256[2 * l];                       // w256^2l
  const float2 T3 = tw256[3 * l];                       // w256^3l (3l<=189)
  const float2 TB = tw256[2 * K2];                      // e^{-2pi i 4K2/512}
  const float2 TY0 = TB;
  const float2 TY1 = cmul(TB, make_float2(0.9999247018391445f, -0.012271538285719925f));
  const float2 TY2 = cmul(TB, make_float2(0.9996988186962042f, -0.024541228522912288f));
  const float2 TY3 = cmul(TB, make_float2(0.9993223845883495f, -0.036807222941358832f));
  const int m0 = __brev((unsigned)((64 - K2) & 63)) >> 26;  // k1=0 partner lane
  const bool h32 = l & 32, h16 = l & 16, h8 = l & 8;
  const bool h4 = l & 4, h2 = l & 2, h1 = l & 1;

  const long plane = (long)BATCH * NF * NT;
  const long pb = (long)b * NF * NT;

  // ---- each wave: 2 frames, full FFT in regs + shuffles ----
  #pragma unroll 1
  for (int it = 0; it < 2; ++it) {
    const int fi = wv * 2 + it;
    const float* xf = xs + fi * INC;

    // pack z[m]=y[2m]+i*y[2m+1], m=l+64j -> radix-4 over j (natural k1 out)
    float2 z0, z1, z2, z3;
    { int n = 2 * l;       float2 xv = *(const float2*)&xf[n], wv2 = *(const float2*)&win[n];
      z0 = make_float2(xv.x * wv2.x, xv.y * wv2.y); }
    { int n = 2 * l + 128; float2 xv = *(const float2*)&xf[n], wv2 = *(const float2*)&win[n];
      z1 = make_float2(xv.x * wv2.x, xv.y * wv2.y); }
    { int n = 2 * l + 256; float2 xv = *(const float2*)&xf[n], wv2 = *(const float2*)&win[n];
      z2 = make_float2(xv.x * wv2.x, xv.y * wv2.y); }
    if (l < 8) {
      int n = 2 * l + 384; float2 xv = *(const float2*)&xf[n], wv2 = *(const float2*)&win[n];
      z3 = make_float2(xv.x * wv2.x, xv.y * wv2.y);
    } else z3 = make_float2(0.f, 0.f);

    float2 s02 = make_float2(z0.x + z2.x, z0.y + z2.y);
    float2 d02 = make_float2(z0.x - z2.x, z0.y - z2.y);
    float2 s13 = make_float2(z1.x + z3.x, z1.y + z3.y);
    float2 d13 = make_float2(z1.x - z3.x, z1.y - z3.y);
    float2 V0 = make_float2(s02.x + s13.x, s02.y + s13.y);
    float2 V2 = cmul(make_float2(s02.x - s13.x, s02.y - s13.y), T2);
    float2 V1 = cmul(make_float2(d02.x + d13.y, d02.y - d13.x), T1); // F1=t1-i*t3
    float2 V3 = cmul(make_float2(d02.x - d13.y, d02.y + d13.x), T3); // F3=t1+i*t3

    // 64-pt DIF FFT across lanes (natural in, brev6 out), for each c
    LSTG(V0, h32, 32, TW0) LSTG(V1, h32, 32, TW0)
    LSTG(V2, h32, 32, TW0) LSTG(V3, h32, 32, TW0)
    LSTG(V0, h16, 16, TW1) LSTG(V1, h16, 16, TW1)
    LSTG(V2, h16, 16, TW1) LSTG(V3, h16, 16, TW1)
    LSTG(V0, h8,  8,  TW2) LSTG(V1, h8,  8,  TW2)
    LSTG(V2, h8,  8,  TW2) LSTG(V3, h8,  8,  TW2)
    LSTG(V0, h4,  4,  TW3) LSTG(V1, h4,  4,  TW3)
    LSTG(V2, h4,  4,  TW3) LSTG(V3, h4,  4,  TW3)
    LSTG(V0, h2,  2,  TW4) LSTG(V1, h2,  2,  TW4)
    LSTG(V2, h2,  2,  TW4) LSTG(V3, h2,  2,  TW4)
    LSTGN(V0, h1, 1) LSTGN(V1, h1, 1) LSTGN(V2, h1, 1) LSTGN(V3, h1, 1)
    // now Vc = Z[4*K2 + c]

    // in-register rFFT unpack partners
    float2 P1 = sx(V1, 63), P2 = sx(V2, 63), P3 = sx(V3, 63);
    float2 P0 = make_float2(__shfl(V0.x, m0), __shfl(V0.y, m0));

    float* mrow = magb + fi * MPLD;
    float* prow = phb + fi * MPLD;
    emitY(V0, P0, TY0, 4 * K2 + 0, K2,       xf, w, mrow, prow);
    emitY(V1, P3, TY1, 4 * K2 + 1, K2 + 64,  xf, w, mrow, prow);
    emitY(V2, P2, TY2, 4 * K2 + 2, K2 + 128, xf, w, mrow, prow);
    emitY(V3, P1, TY3, 4 * K2 + 3, K2 + 192, xf, w, mrow, prow);
    if (l == 0) {                           // Y[256] = Re Z0 - Im Z0
      emitMP(V0.x - V0.y, 0.f, 256, 256, xf, w, mrow, prow);
    }
  }
  __syncthreads();

  // ---- coalesced flush: 8 consecutive t per f-row (32B), both planes ----
  for (int r = 0; r < 9; ++r) {
    int tau = r * 256 + tid;
    if (tau < FPB * NF) {                   // 2056
      int t8 = tau & 7;
      int p = tau >> 3;                     // 0..256
      int tt = t0 + t8;
      if (tt < NT) {
        int col = (p == 256) ? 256 : ((p >> 2) | ((p & 3) << 6));
        long o = pb + (long)p * NT + tt;
        out[o] = magb[t8 * MPLD + col];
        out[o + plane] = phb[t8 * MPLD + col];
      }
    }
  }
}

extern "C" void kernel_launch(void* const* d_in, const int* in_sizes, int n_in,
                              void* d_out, int out_size, void* d_ws, size_t ws_size,
                              hipStream_t stream) {
  const float* x = (const float*)d_in[0];   // (16, 160000) fp32
  const float* w = (const float*)d_in[1];   // (514, 1, 400) fp32
  float* out = (float*)d_out;

  dim3 grid(NTB, BATCH);                    // 201 x 16 = 3216 blocks
  stft_fft7<<<grid, dim3(256), 0, stream>>>(x, w, out);
}